// Round 6
// baseline (1607.618 us; speedup 1.0000x reference)
//
#include <hip/hip_runtime.h>
#include <hip/hip_bf16.h>

// CfC cell via three bf16 MFMA GEMMs. Block 128x256, 512 thr = 8 waves (2Mx4N),
// per-wave 64x64 (acc=64 VGPR). A staged via global_load_lds into 4 rotating
// 8KB LDS slabs (32KB total -> 2 blocks/CU with VGPR<=128). B is NOT staged:
// pre-packed fragment-order buffer, loaded dwordx4 from L2, double-banked,
// prefetch depth 2. Counted vmcnt ledger; st_16x32 swizzle on A; setprio MFMA.

typedef unsigned short u16;
typedef __bf16 bf16x8_t __attribute__((ext_vector_type(8)));
typedef float f32x4_t __attribute__((ext_vector_type(4)));
typedef u16 u16x8_t __attribute__((ext_vector_type(8)));

#define M_TOTAL 131072  // B*T = 128*1024

__device__ __forceinline__ u16 f2bf(float f) {
  union { float f; unsigned u; } v; v.f = f;
  unsigned r = v.u + 0x7FFFu + ((v.u >> 16) & 1u);  // RNE
  return (u16)(r >> 16);
}

__device__ __forceinline__ float fast_tanh(float x) {
  x = fminf(15.f, fmaxf(-15.f, x));
  float e = __expf(2.f * x);
  return (e - 1.f) * __builtin_amdgcn_rcpf(e + 1.f);
}

__device__ __forceinline__ float fast_sigmoid(float x) {
  return __builtin_amdgcn_rcpf(1.f + __expf(-x));
}

__device__ __forceinline__ void gload_lds16(const void* g, void* l) {
  __builtin_amdgcn_global_load_lds(
      (const __attribute__((address_space(1))) unsigned int*)g,
      (__attribute__((address_space(3))) unsigned int*)l,
      16, 0, 0);
}

// ---------------- prep kernels ----------------

__global__ void prep_x(const float* __restrict__ inp, const float* __restrict__ hx,
                       u16* __restrict__ X) {
  const int total = M_TOTAL * 96;
  int stride = gridDim.x * blockDim.x;
  for (int v = blockIdx.x * blockDim.x + threadIdx.x; v < total; v += stride) {
    int m = v / 96; int c = v - m * 96;
    const float* src = (c < 32) ? (inp + (size_t)m * 256 + (c << 3))
                                : (hx + (size_t)m * 512 + ((size_t)(c - 32) << 3));
    f32x4_t a = *(const f32x4_t*)src;
    f32x4_t b = *(const f32x4_t*)(src + 4);
    u16x8_t o;
    o[0]=f2bf(a[0]); o[1]=f2bf(a[1]); o[2]=f2bf(a[2]); o[3]=f2bf(a[3]);
    o[4]=f2bf(b[0]); o[5]=f2bf(b[1]); o[6]=f2bf(b[2]); o[7]=f2bf(b[3]);
    *(u16x8_t*)(X + (size_t)m * 768 + (c << 3)) = o;
  }
}

// Pack all B matrices into MFMA-fragment order:
// Bpack[t][g][lane] (16B each) : col = g*16 + (lane&15), k = t*32 + (lane>>4)*8 + e.
// Head weights interleaved per 16-col block (g&3 = head, n = (g>>2)*16 + (l&15)).
__global__ void prep_w(const float* __restrict__ W0, const float* __restrict__ W1,
                       const float* __restrict__ Wf1, const float* __restrict__ Wf2,
                       const float* __restrict__ Wta, const float* __restrict__ Wtb,
                       const float* __restrict__ bf1, const float* __restrict__ bf2,
                       const float* __restrict__ bta, const float* __restrict__ btb,
                       u16* __restrict__ W0P, u16* __restrict__ W1P,
                       u16* __restrict__ WhP, float* __restrict__ biasi) {
  int id = blockIdx.x * blockDim.x + threadIdx.x;
  u16x8_t o;
  if (id < 98304) {                       // W0P: K=768 (24 slabs), N=1024 (64 g)
    int l = id & 63, r = id >> 6;
    int g = r % 64, t = r / 64;
    int col = g * 16 + (l & 15), kb = t * 32 + ((l >> 4) << 3);
#pragma unroll
    for (int e = 0; e < 8; ++e) o[e] = f2bf(W0[(size_t)(kb + e) * 1024 + col]);
    *((u16x8_t*)W0P + id) = o;
  } else if (id < 229376) {               // W1P: K=1024 (32 slabs), N=1024 (64 g)
    int id2 = id - 98304;
    int l = id2 & 63, r = id2 >> 6;
    int g = r & 63, t = r >> 6;
    int col = g * 16 + (l & 15), kb = t * 32 + ((l >> 4) << 3);
#pragma unroll
    for (int e = 0; e < 8; ++e) o[e] = f2bf(W1[(size_t)(kb + e) * 1024 + col]);
    *((u16x8_t*)W1P + id2) = o;
  } else if (id < 491520) {               // WhP: K=1024 (32 slabs), N=2048 (128 g)
    int id3 = id - 229376;
    int l = id3 & 63, r = id3 >> 6;
    int g = r & 127, t = r >> 7;
    int head = g & 3;
    int n = (g >> 2) * 16 + (l & 15), kb = t * 32 + ((l >> 4) << 3);
    const float* W = (head == 0) ? Wf1 : (head == 1) ? Wf2 : (head == 2) ? Wta : Wtb;
#pragma unroll
    for (int e = 0; e < 8; ++e) o[e] = f2bf(W[(size_t)(kb + e) * 512 + n]);
    *((u16x8_t*)WhP + id3) = o;
  } else if (id < 492032) {               // interleaved head bias
    int h = id - 491520;
    int base = ((h >> 4) << 6) + (h & 15);
    biasi[base +  0] = bf1[h];
    biasi[base + 16] = bf2[h];
    biasi[base + 32] = bta[h];
    biasi[base + 48] = btb[h];
  }
}

// ---------------- GEMM: A-in-LDS (4 slabs), B-from-L2 (packed) ----------------

#define BARX()   do { __builtin_amdgcn_s_barrier(); __builtin_amdgcn_sched_barrier(0); } while(0)
#define LGKM0()  do { asm volatile("s_waitcnt lgkmcnt(0)" ::: "memory"); __builtin_amdgcn_sched_barrier(0); } while(0)
#define SCHEDB() __builtin_amdgcn_sched_barrier(0)
#define WAITVM_(n) do { asm volatile("s_waitcnt vmcnt(" #n ")" ::: "memory"); __builtin_amdgcn_sched_barrier(0); } while(0)
#define WAITVM(n) WAITVM_(n)

template<int K, int NI, int EPI>
__global__ __launch_bounds__(512, 4)
void gemmB(const u16* __restrict__ A, const char* __restrict__ Bp,
           const float* __restrict__ bias, const float* __restrict__ ts,
           void* __restrict__ Cout)
{
  constexpr int NTn = NI / 256;
  constexpr int G64 = NI / 16;             // 16-col fragment blocks
  constexpr size_t G64K = (size_t)G64 * 1024;  // bytes per k-slab of Bpack
  constexpr int NT = K / 32;               // k-steps
  constexpr int NWG = (M_TOTAL / 128) * NTn;
  __shared__ __align__(16) char smem[32768];   // 4 A-slabs x [128][32] bf16

  const int bid = ((blockIdx.x & 7) * (NWG >> 3)) + (blockIdx.x >> 3);  // XCD swizzle
  const int mt = bid / NTn, nt = bid % NTn;
  const int tileM = mt * 128, tileN = nt * 256;

  const int tid = threadIdx.x, w = tid >> 6, l = tid & 63;
  const int wm = w >> 2, wn = w & 3;

  // A stage: wave w stages rows 16w..16w+15 of each slab (1 KB chunk, 1 load).
  // st_16x32 swizzle: linear LDS dest + inverse-swizzled global k-offset.
  const int laneK = ((l & 3) << 3) ^ (((l >> 5) & 1) << 4);   // elements
  const u16* aS = A + (size_t)(tileM + 16 * w + (l >> 2)) * K + laneK;
  char* ldsW = smem + (w << 10);
  // A fragment read (swizzle applied on read)
  const int colRs = ((l >> 4) << 4) ^ (((l >> 3) & 1) << 5);
  const char* aRd = smem + (wm * 64 + (l & 15)) * 64 + colRs;
  // B packed: wave's 4 fragment blocks start at g = (tileN>>4) + wn*4
  const char* bp0 = Bp + ((size_t)(((tileN >> 4) + wn * 4) * 64 + l) << 4);

  f32x4_t acc[4][4];
#pragma unroll
  for (int i = 0; i < 4; ++i)
#pragma unroll
    for (int j = 0; j < 4; ++j) acc[i][j] = f32x4_t{0.f, 0.f, 0.f, 0.f};

  bf16x8_t af[4], ba[4], bb[4];

// one 32-k step: W1N = counted vmcnt for own A-stage residency (before barrier);
// reads slot SLOT, computes with bank BK, optionally stages STPTR->STSLOT and
// reloads BK from BLPTR (B for step j+2) after the MFMA cluster.
#define GSTEP(W1N, SLOT, BK, DOST, STPTR, STSLOT, DOBL, BLPTR) do { \
    WAITVM(W1N); BARX(); \
    if (DOST) gload_lds16((STPTR), ldsW + (STSLOT) * 8192); \
    af[0] = *(const bf16x8_t*)(aRd + (SLOT) * 8192 +    0); \
    af[1] = *(const bf16x8_t*)(aRd + (SLOT) * 8192 + 1024); \
    af[2] = *(const bf16x8_t*)(aRd + (SLOT) * 8192 + 2048); \
    af[3] = *(const bf16x8_t*)(aRd + (SLOT) * 8192 + 3072); \
    LGKM0(); \
    __builtin_amdgcn_s_setprio(1); \
    _Pragma("unroll") for (int m_ = 0; m_ < 4; ++m_) \
      _Pragma("unroll") for (int n_ = 0; n_ < 4; ++n_) \
        acc[m_][n_] = __builtin_amdgcn_mfma_f32_16x16x32_bf16( \
            af[m_], BK[n_], acc[m_][n_], 0, 0, 0); \
    __builtin_amdgcn_s_setprio(0); \
    SCHEDB(); \
    if (DOBL) { \
      BK[0] = *(const bf16x8_t*)((BLPTR)); \
      BK[1] = *(const bf16x8_t*)((BLPTR) + 1024); \
      BK[2] = *(const bf16x8_t*)((BLPTR) + 2048); \
      BK[3] = *(const bf16x8_t*)((BLPTR) + 3072); \
    } \
    SCHEDB(); \
  } while(0)

  // prologue: B0 -> ba, B1 -> bb, then stage slabs 0,1,2
  ba[0] = *(const bf16x8_t*)(bp0);
  ba[1] = *(const bf16x8_t*)(bp0 + 1024);
  ba[2] = *(const bf16x8_t*)(bp0 + 2048);
  ba[3] = *(const bf16x8_t*)(bp0 + 3072);
  bb[0] = *(const bf16x8_t*)(bp0 + G64K);
  bb[1] = *(const bf16x8_t*)(bp0 + G64K + 1024);
  bb[2] = *(const bf16x8_t*)(bp0 + G64K + 2048);
  bb[3] = *(const bf16x8_t*)(bp0 + G64K + 3072);
  SCHEDB();
  gload_lds16(aS,      ldsW);
  gload_lds16(aS + 32, ldsW + 8192);
  gload_lds16(aS + 64, ldsW + 16384);
  SCHEDB();

  // head peel: j = 0..3 (stage s3..s6, load B2..B5)
  GSTEP(2,  0, ba, 1, aS +  96, 3, 1, bp0 + 2 * G64K);
  GSTEP(6,  1, bb, 1, aS + 128, 0, 1, bp0 + 3 * G64K);
  GSTEP(10, 2, ba, 1, aS + 160, 1, 1, bp0 + 4 * G64K);
  GSTEP(14, 3, bb, 1, aS + 192, 2, 1, bp0 + 5 * G64K);

  // steady: j = 4 .. NT-5 (stage j+3, load B(j+2))
  const u16* aSt = aS + 7 * 32;
  const char* bSt = bp0 + 6 * G64K;
#pragma unroll 1
  for (int it = 0; it < (NT - 8) / 4; ++it) {
    GSTEP(14, 0, ba, 1, aSt,      3, 1, bSt);
    GSTEP(14, 1, bb, 1, aSt + 32, 0, 1, bSt + G64K);
    GSTEP(14, 2, ba, 1, aSt + 64, 1, 1, bSt + 2 * G64K);
    GSTEP(14, 3, bb, 1, aSt + 96, 2, 1, bSt + 3 * G64K);
    aSt += 128; bSt += 4 * G64K;
  }

  // tail: j = NT-4 .. NT-1
  GSTEP(14, 0, ba, 1, aS + (size_t)(NT - 1) * 32, 3, 1, bp0 + (size_t)(NT - 2) * G64K);
  GSTEP(14, 1, bb, 0, aS, 0, 1, bp0 + (size_t)(NT - 1) * G64K);
  GSTEP(13, 2, ba, 0, aS, 0, 0, bp0);
  GSTEP(8,  3, bb, 0, aS, 0, 0, bp0);

  // ---------------- epilogue ----------------
  // C/D layout: col = lane&15, row = (lane>>4)*4 + reg (m89-verified)
  const int colBase = tileN + wn * 64 + (l & 15);
  float bv[4];
  bv[0] = bias[colBase];      bv[1] = bias[colBase + 16];
  bv[2] = bias[colBase + 32]; bv[3] = bias[colBase + 48];

  if constexpr (EPI == 0) {
    u16* C = (u16*)Cout;
    const int rowB = tileM + wm * 64 + ((l >> 4) << 2);
#pragma unroll
    for (int m = 0; m < 4; ++m)
#pragma unroll
      for (int nn = 0; nn < 4; ++nn)
#pragma unroll
        for (int j = 0; j < 4; ++j) {
          float v = acc[m][nn][j] + bv[nn];
          float t = 1.7159f * fast_tanh(0.666f * v);
          C[(size_t)(rowB + m * 16 + j) * NI + colBase + nn * 16] = f2bf(t);
        }
  } else {
    // heads interleaved per 16-col block: nn == head
    const int hg = ((tileN + wn * 64) >> 6) * 16 + (l & 15);
    float* out = (float*)Cout;
#pragma unroll
    for (int m = 0; m < 4; ++m)
#pragma unroll
      for (int j = 0; j < 4; ++j) {
        const int rl = wm * 64 + m * 16 + ((l >> 4) << 2) + j;
        const float tsv = ts[tileM + rl];   // L1 broadcast hit
        float ff1 = fast_tanh(acc[m][0][j] + bv[0]);
        float ff2 = fast_tanh(acc[m][1][j] + bv[1]);
        float s = fast_sigmoid((acc[m][2][j] + bv[2]) * tsv + (acc[m][3][j] + bv[3]));
        out[(size_t)(tileM + rl) * 512 + hg] = ff1 + s * (ff2 - ff1);
      }
  }
#undef GSTEP
}

// ---------------- launch ----------------

extern "C" void kernel_launch(void* const* d_in, const int* in_sizes, int n_in,
                              void* d_out, int out_size, void* d_ws, size_t ws_size,
                              hipStream_t stream) {
  const float* input = (const float*)d_in[0];
  const float* hx    = (const float*)d_in[1];
  const float* ts    = (const float*)d_in[2];
  const float* W0    = (const float*)d_in[3];
  const float* b0    = (const float*)d_in[4];
  const float* W1    = (const float*)d_in[5];
  const float* b1    = (const float*)d_in[6];
  const float* Wff1  = (const float*)d_in[7];
  const float* bff1  = (const float*)d_in[8];
  const float* Wff2  = (const float*)d_in[9];
  const float* bff2  = (const float*)d_in[10];
  const float* Wta   = (const float*)d_in[11];
  const float* bta   = (const float*)d_in[12];
  const float* Wtb   = (const float*)d_in[13];
  const float* btb   = (const float*)d_in[14];

  const size_t WS_NEEDED = 544743424ull;
  if (ws_size < WS_NEEDED) return;
  char* ws = (char*)d_ws;
  u16* Xcat = (u16*)(ws);                      // [M,768] bf16, reused as X2 [M,1024]
  u16* X2   = (u16*)(ws);
  u16* X1   = (u16*)(ws + 268435456ull);       // [M,1024] bf16
  u16* W0P  = (u16*)(ws + 536870912ull);       // packed frags, 1.5 MB
  u16* W1P  = (u16*)(ws + 538443776ull);       // packed frags, 2 MB
  u16* WhP  = (u16*)(ws + 540540928ull);       // packed frags, 4 MB (head-interleaved)
  float* biasi = (float*)(ws + 544735232ull);  // [2048]

  prep_x<<<2048, 256, 0, stream>>>(input, hx, Xcat);
  prep_w<<<1922, 256, 0, stream>>>(W0, W1, Wff1, Wff2, Wta, Wtb,
                                   bff1, bff2, bta, btb, W0P, W1P, WhP, biasi);

  gemmB<768, 1024, 0><<<4096, 512, 0, stream>>>(Xcat, (const char*)W0P, b0, nullptr, X1);
  gemmB<1024, 1024, 0><<<4096, 512, 0, stream>>>(X1, (const char*)W1P, b1, nullptr, X2);
  gemmB<1024, 2048, 1><<<8192, 512, 0, stream>>>(X2, (const char*)WhP, biasi, ts, d_out);
}

// Round 7
// 1220.625 us; speedup vs baseline: 1.3170x; 1.3170x over previous
//
#include <hip/hip_runtime.h>
#include <hip/hip_bf16.h>

// CfC cell via three bf16 MFMA GEMMs. Block 256x256, 512 thr = 8 waves (2Mx4N),
// per-wave 128x64 (acc[8][4] in AGPRs). A staged via global_load_lds into 4
// rotating 16KB LDS slabs (64KB -> 2 blocks/CU). B NOT staged: pre-packed
// fragment-order buffer read dwordx4 from L2 into double-banked registers,
// prefetch depth 2. Counted vmcnt ledger (6 vm-ops/step); st_16x32 swizzle on A.

typedef unsigned short u16;
typedef __bf16 bf16x8_t __attribute__((ext_vector_type(8)));
typedef float f32x4_t __attribute__((ext_vector_type(4)));
typedef u16 u16x8_t __attribute__((ext_vector_type(8)));

#define M_TOTAL 131072  // B*T = 128*1024

__device__ __forceinline__ u16 f2bf(float f) {
  union { float f; unsigned u; } v; v.f = f;
  unsigned r = v.u + 0x7FFFu + ((v.u >> 16) & 1u);  // RNE
  return (u16)(r >> 16);
}

__device__ __forceinline__ float fast_tanh(float x) {
  x = fminf(15.f, fmaxf(-15.f, x));
  float e = __expf(2.f * x);
  return (e - 1.f) * __builtin_amdgcn_rcpf(e + 1.f);
}

__device__ __forceinline__ float fast_sigmoid(float x) {
  return __builtin_amdgcn_rcpf(1.f + __expf(-x));
}

__device__ __forceinline__ void gload_lds16(const void* g, void* l) {
  __builtin_amdgcn_global_load_lds(
      (const __attribute__((address_space(1))) unsigned int*)g,
      (__attribute__((address_space(3))) unsigned int*)l,
      16, 0, 0);
}

// ---------------- prep kernels ----------------

__global__ void prep_x(const float* __restrict__ inp, const float* __restrict__ hx,
                       u16* __restrict__ X) {
  const int total = M_TOTAL * 96;
  int stride = gridDim.x * blockDim.x;
  for (int v = blockIdx.x * blockDim.x + threadIdx.x; v < total; v += stride) {
    int m = v / 96; int c = v - m * 96;
    const float* src = (c < 32) ? (inp + (size_t)m * 256 + (c << 3))
                                : (hx + (size_t)m * 512 + ((size_t)(c - 32) << 3));
    f32x4_t a = *(const f32x4_t*)src;
    f32x4_t b = *(const f32x4_t*)(src + 4);
    u16x8_t o;
    o[0]=f2bf(a[0]); o[1]=f2bf(a[1]); o[2]=f2bf(a[2]); o[3]=f2bf(a[3]);
    o[4]=f2bf(b[0]); o[5]=f2bf(b[1]); o[6]=f2bf(b[2]); o[7]=f2bf(b[3]);
    *(u16x8_t*)(X + (size_t)m * 768 + (c << 3)) = o;
  }
}

// Pack all B matrices into MFMA-fragment order:
// Bpack[t][g][lane] (16B each): col = g*16 + (lane&15), k = t*32 + (lane>>4)*8 + e.
// Head weights interleaved per 16-col block (g&3 = head, n = (g>>2)*16 + (l&15)).
__global__ void prep_w(const float* __restrict__ W0, const float* __restrict__ W1,
                       const float* __restrict__ Wf1, const float* __restrict__ Wf2,
                       const float* __restrict__ Wta, const float* __restrict__ Wtb,
                       const float* __restrict__ bf1, const float* __restrict__ bf2,
                       const float* __restrict__ bta, const float* __restrict__ btb,
                       u16* __restrict__ W0P, u16* __restrict__ W1P,
                       u16* __restrict__ WhP, float* __restrict__ biasi) {
  int id = blockIdx.x * blockDim.x + threadIdx.x;
  u16x8_t o;
  if (id < 98304) {                       // W0P: K=768 (24 slabs), N=1024 (64 g)
    int l = id & 63, r = id >> 6;
    int g = r % 64, t = r / 64;
    int col = g * 16 + (l & 15), kb = t * 32 + ((l >> 4) << 3);
#pragma unroll
    for (int e = 0; e < 8; ++e) o[e] = f2bf(W0[(size_t)(kb + e) * 1024 + col]);
    *((u16x8_t*)W0P + id) = o;
  } else if (id < 229376) {               // W1P: K=1024 (32 slabs), N=1024 (64 g)
    int id2 = id - 98304;
    int l = id2 & 63, r = id2 >> 6;
    int g = r & 63, t = r >> 6;
    int col = g * 16 + (l & 15), kb = t * 32 + ((l >> 4) << 3);
#pragma unroll
    for (int e = 0; e < 8; ++e) o[e] = f2bf(W1[(size_t)(kb + e) * 1024 + col]);
    *((u16x8_t*)W1P + id2) = o;
  } else if (id < 491520) {               // WhP: K=1024 (32 slabs), N=2048 (128 g)
    int id3 = id - 229376;
    int l = id3 & 63, r = id3 >> 6;
    int g = r & 127, t = r >> 7;
    int head = g & 3;
    int n = (g >> 2) * 16 + (l & 15), kb = t * 32 + ((l >> 4) << 3);
    const float* W = (head == 0) ? Wf1 : (head == 1) ? Wf2 : (head == 2) ? Wta : Wtb;
#pragma unroll
    for (int e = 0; e < 8; ++e) o[e] = f2bf(W[(size_t)(kb + e) * 512 + n]);
    *((u16x8_t*)WhP + id3) = o;
  } else if (id < 492032) {               // interleaved head bias
    int h = id - 491520;
    int base = ((h >> 4) << 6) + (h & 15);
    biasi[base +  0] = bf1[h];
    biasi[base + 16] = bf2[h];
    biasi[base + 32] = bta[h];
    biasi[base + 48] = btb[h];
  }
}

// ---------------- GEMM: A-in-LDS (4 x 16KB slabs), B-from-L2 (packed) ----------------

#define BARX()   do { __builtin_amdgcn_s_barrier(); __builtin_amdgcn_sched_barrier(0); } while(0)
#define LGKM0()  do { asm volatile("s_waitcnt lgkmcnt(0)" ::: "memory"); __builtin_amdgcn_sched_barrier(0); } while(0)
#define SCHEDB() __builtin_amdgcn_sched_barrier(0)
#define WAITVM_(n) do { asm volatile("s_waitcnt vmcnt(" #n ")" ::: "memory"); __builtin_amdgcn_sched_barrier(0); } while(0)
#define WAITVM(n) WAITVM_(n)

template<int K, int NI, int EPI>
__global__ __launch_bounds__(512, 2)
void gemmC(const u16* __restrict__ A, const char* __restrict__ Bp,
           const float* __restrict__ bias, const float* __restrict__ ts,
           void* __restrict__ Cout)
{
  constexpr int NTn = NI / 256;
  constexpr int G64 = NI / 16;                 // 16-col fragment blocks per k-slab
  constexpr size_t G64K = (size_t)G64 * 1024;  // bytes per k-slab of Bpack
  constexpr int NT = K / 32;                   // k-steps
  constexpr int NWG = (M_TOTAL / 256) * NTn;
  __shared__ __align__(16) char smem[65536];   // 4 A-slabs x [256][32] bf16

  const int bid = ((blockIdx.x & 7) * (NWG >> 3)) + (blockIdx.x >> 3);  // XCD swizzle
  const int mt = bid / NTn, nt = bid % NTn;
  const int tileM = mt * 256, tileN = nt * 256;

  const int tid = threadIdx.x, w = tid >> 6, l = tid & 63;
  const int wm = w >> 2, wn = w & 3;

  // A staging: wave w stages rows 32w..32w+31 of each slab (2 x 1KB chunks).
  // st_16x32 swizzle: linear LDS dest + inverse-swizzled global k-offset.
  const int laneK = ((l & 3) << 3) ^ (((l >> 5) & 1) << 4);   // elements
  const u16* aS0 = A + (size_t)(tileM + 32 * w + (l >> 2)) * K + laneK;
  const u16* aS1 = aS0 + (size_t)16 * K;
  char* ldsW = smem + (w << 11);               // wave's 2KB region within a slab
  // A fragment read (swizzle applied on read)
  const int colRs = ((l >> 4) << 4) ^ (((l >> 3) & 1) << 5);
  const char* aRd = smem + (wm * 128 + (l & 15)) * 64 + colRs;
  // B packed: wave's 4 fragment blocks start at g = (tileN>>4) + wn*4
  const char* bp0 = Bp + ((size_t)(((tileN >> 4) + wn * 4) * 64 + l) << 4);

  f32x4_t acc[8][4];
#pragma unroll
  for (int i = 0; i < 8; ++i)
#pragma unroll
    for (int j = 0; j < 4; ++j) acc[i][j] = f32x4_t{0.f, 0.f, 0.f, 0.f};

  bf16x8_t af[8], ba[4], bb[4];

#define LDB(BK, OFF) do { \
    BK[0] = *(const bf16x8_t*)(bp0 + (OFF)); \
    BK[1] = *(const bf16x8_t*)(bp0 + (OFF) + 1024); \
    BK[2] = *(const bf16x8_t*)(bp0 + (OFF) + 2048); \
    BK[3] = *(const bf16x8_t*)(bp0 + (OFF) + 3072); } while(0)

// one 32-k step. W1N = vmcnt ledger for own A-stage residency of SLOT.
// Stages slot (SLOT+3)&3 from k-offset TOFF if DOST; reloads bank BK from
// Bpack+BLOFF (B for step j+2) after the MFMA cluster if DOBL.
#define GSTEP(W1N, SLOT, BK, DOST, TOFF, DOBL, BLOFF) do { \
    WAITVM(W1N); BARX(); \
    if (DOST) { \
      gload_lds16(aS0 + (TOFF), ldsW + (((SLOT) + 3) & 3) * 16384); \
      gload_lds16(aS1 + (TOFF), ldsW + (((SLOT) + 3) & 3) * 16384 + 1024); \
    } \
    _Pragma("unroll") for (int m_ = 0; m_ < 8; ++m_) \
      af[m_] = *(const bf16x8_t*)(aRd + (SLOT) * 16384 + m_ * 1024); \
    LGKM0(); \
    __builtin_amdgcn_s_setprio(1); \
    _Pragma("unroll") for (int m_ = 0; m_ < 8; ++m_) \
      _Pragma("unroll") for (int n_ = 0; n_ < 4; ++n_) \
        acc[m_][n_] = __builtin_amdgcn_mfma_f32_16x16x32_bf16( \
            af[m_], BK[n_], acc[m_][n_], 0, 0, 0); \
    __builtin_amdgcn_s_setprio(0); \
    SCHEDB(); \
    if (DOBL) LDB(BK, BLOFF); \
    SCHEDB(); \
  } while(0)

  // prologue: B0->ba, B1->bb (8 vm ops), then stage slabs 0,1,2 (6 vm ops)
  LDB(ba, 0);
  LDB(bb, G64K);
  SCHEDB();
  gload_lds16(aS0,      ldsW);
  gload_lds16(aS1,      ldsW + 1024);
  gload_lds16(aS0 + 32, ldsW + 16384);
  gload_lds16(aS1 + 32, ldsW + 16384 + 1024);
  gload_lds16(aS0 + 64, ldsW + 32768);
  gload_lds16(aS1 + 64, ldsW + 32768 + 1024);
  SCHEDB();

  // peel j=0..3 (ledger: 4, 8, 12, 16)
  GSTEP(4,  0, ba, 1, 3 * 32, 1, 2 * G64K);
  GSTEP(8,  1, bb, 1, 4 * 32, 1, 3 * G64K);
  GSTEP(12, 2, ba, 1, 5 * 32, 1, 4 * G64K);
  GSTEP(16, 3, bb, 1, 6 * 32, 1, 5 * G64K);

  // steady j=4..NT-5: stage s(j+3), load B(j+2)
  {
    size_t tOff = 7 * 32;
    size_t blOff = 6 * G64K;
#pragma unroll 1
    for (int it = 0; it < (NT - 8) / 4; ++it) {
      GSTEP(16, 0, ba, 1, tOff,      1, blOff);
      GSTEP(16, 1, bb, 1, tOff + 32, 1, blOff + G64K);
      GSTEP(16, 2, ba, 1, tOff + 64, 1, blOff + 2 * G64K);
      GSTEP(16, 3, bb, 1, tOff + 96, 1, blOff + 3 * G64K);
      tOff += 128; blOff += 4 * G64K;
    }
  }

  // tail j=NT-4..NT-1 (ledger: 16, 16, 14, 8)
  GSTEP(16, 0, ba, 1, (size_t)(NT - 1) * 32, 1, (size_t)(NT - 2) * G64K);
  GSTEP(16, 1, bb, 0, 0, 1, (size_t)(NT - 1) * G64K);
  GSTEP(14, 2, ba, 0, 0, 0, 0);
  GSTEP(8,  3, bb, 0, 0, 0, 0);

  // ---------------- epilogue (no LDS use) ----------------
  // C/D layout: col = lane&15, row = (lane>>4)*4 + reg (m89-verified)
  const int colBase = tileN + wn * 64 + (l & 15);
  float bv[4];
  bv[0] = bias[colBase];      bv[1] = bias[colBase + 16];
  bv[2] = bias[colBase + 32]; bv[3] = bias[colBase + 48];

  if constexpr (EPI == 0) {
    u16* C = (u16*)Cout;
    const int rowB = tileM + wm * 128 + ((l >> 4) << 2);
#pragma unroll
    for (int m = 0; m < 8; ++m)
#pragma unroll
      for (int nn = 0; nn < 4; ++nn)
#pragma unroll
        for (int j = 0; j < 4; ++j) {
          float v = acc[m][nn][j] + bv[nn];
          float t = 1.7159f * fast_tanh(0.666f * v);
          C[(size_t)(rowB + m * 16 + j) * NI + colBase + nn * 16] = f2bf(t);
        }
  } else {
    // heads interleaved per 16-col block: nn == head
    const int hg = ((tileN + wn * 64) >> 6) * 16 + (l & 15);
    float* out = (float*)Cout;
#pragma unroll
    for (int m = 0; m < 8; ++m)
#pragma unroll
      for (int j = 0; j < 4; ++j) {
        const int rl = wm * 128 + m * 16 + ((l >> 4) << 2) + j;
        const float tsv = ts[tileM + rl];   // L1 broadcast hit
        float ff1 = fast_tanh(acc[m][0][j] + bv[0]);
        float ff2 = fast_tanh(acc[m][1][j] + bv[1]);
        float s = fast_sigmoid((acc[m][2][j] + bv[2]) * tsv + (acc[m][3][j] + bv[3]));
        out[(size_t)(tileM + rl) * 512 + hg] = ff1 + s * (ff2 - ff1);
      }
  }
#undef LDB
#undef GSTEP
}

// ---------------- launch ----------------

extern "C" void kernel_launch(void* const* d_in, const int* in_sizes, int n_in,
                              void* d_out, int out_size, void* d_ws, size_t ws_size,
                              hipStream_t stream) {
  const float* input = (const float*)d_in[0];
  const float* hx    = (const float*)d_in[1];
  const float* ts    = (const float*)d_in[2];
  const float* W0    = (const float*)d_in[3];
  const float* b0    = (const float*)d_in[4];
  const float* W1    = (const float*)d_in[5];
  const float* b1    = (const float*)d_in[6];
  const float* Wff1  = (const float*)d_in[7];
  const float* bff1  = (const float*)d_in[8];
  const float* Wff2  = (const float*)d_in[9];
  const float* bff2  = (const float*)d_in[10];
  const float* Wta   = (const float*)d_in[11];
  const float* bta   = (const float*)d_in[12];
  const float* Wtb   = (const float*)d_in[13];
  const float* btb   = (const float*)d_in[14];

  const size_t WS_NEEDED = 544743424ull;
  if (ws_size < WS_NEEDED) return;
  char* ws = (char*)d_ws;
  u16* Xcat = (u16*)(ws);                      // [M,768] bf16, reused as X2 [M,1024]
  u16* X2   = (u16*)(ws);
  u16* X1   = (u16*)(ws + 268435456ull);       // [M,1024] bf16
  u16* W0P  = (u16*)(ws + 536870912ull);       // packed frags, 1.5 MB
  u16* W1P  = (u16*)(ws + 538443776ull);       // packed frags, 2 MB
  u16* WhP  = (u16*)(ws + 540540928ull);       // packed frags, 4 MB (head-interleaved)
  float* biasi = (float*)(ws + 544735232ull);  // [2048]

  prep_x<<<2048, 256, 0, stream>>>(input, hx, Xcat);
  prep_w<<<1922, 256, 0, stream>>>(W0, W1, Wff1, Wff2, Wta, Wtb,
                                   bff1, bff2, bta, btb, W0P, W1P, WhP, biasi);

  gemmC<768, 1024, 0><<<2048, 512, 0, stream>>>(Xcat, (const char*)W0P, b0, nullptr, X1);
  gemmC<1024, 1024, 0><<<2048, 512, 0, stream>>>(X1, (const char*)W1P, b1, nullptr, X2);
  gemmC<1024, 2048, 1><<<4096, 512, 0, stream>>>(X2, (const char*)WhP, biasi, ts, d_out);
}